// Round 2
// baseline (192.828 us; speedup 1.0000x reference)
//
#include <hip/hip_runtime.h>

#define N_PSF 32
#define BC    32
#define Hh    256
#define Ww    256
#define Dd    64              // coarse spatial dim (256/4)
#define BWk   31              // band width
#define PADk  15
#define PX    16              // pixels per block
#define XW    (PX + BWk - 1)  // 46 staged x positions
#define XSTR  36              // xp LDS stride: mult of 4 (b128 align), ≡4 mod 32 (bank spread)
#define WN    36              // wY n-stride (same constraints)
#define WJS   (BWk * WN)      // 1116: per-coarse-x stride
#define NTH   256

__global__ __launch_bounds__(NTH, 4)
void band_kernel(const float* __restrict__ pw,
                 const float* __restrict__ x,
                 float* __restrict__ out)
{
    // wY: [j=6 coarse-x][k=31][n=32(+pad)]  y-interpolated weights
    // xp: [xw=46][bc=32(+pad)]              zero-padded x window
    __shared__ __align__(16) float smem[6 * WJS + XW * XSTR];
    float* wY = smem;
    float* xp = smem + 6 * WJS;

    const int tid = threadIdx.x;
    const int y   = blockIdx.y;
    const int x0  = blockIdx.x * PX;

    const int xi = tid & 15;              // pixel within tile
    const int ng = (tid >> 4) & 3;        // n-group (8 n)
    const int bg = tid >> 6;              // bc-group (8 bc) == wave id

    // --- y interpolation setup (block-uniform), exact scale-4 half-pixel ---
    const int yq = y >> 2, ry = y & 3;
    const int y0i = yq + ((ry < 2) ? -1 : 0);
    const float fy = 0.125f + 0.25f * (float)((ry + 2) & 3);  // {.625,.875,.125,.375}
    const int y0c = (y0i < 0) ? 0 : y0i;
    const int y1c = (y0i + 1 > Dd - 1) ? Dd - 1 : (y0i + 1);
    const int cxbase = (x0 >> 2) - 1;     // leftmost coarse col needed

    // --- stage x window: xp[xw][bc], zero-padded ---
    #pragma unroll
    for (int i = 0; i < 6; ++i) {
        int t = tid + i * NTH;
        if (t < XW * BC) {
            int xw = t % XW;
            int bc = t / XW;
            int gx = x0 - PADk + xw;
            float v = 0.f;
            if ((unsigned)gx < (unsigned)Ww) v = x[(bc * Hh + y) * Ww + gx];
            xp[xw * XSTR + bc] = v;
        }
    }

    // --- stage y-interpolated coarse weights: wY[j][k][n] ---
    // tasks: (j 0..5) x (n 0..31) x (k 0..30); lanes walk k => coalesced rows
    {
        const int k  = tid & 31;
        const int nb = tid >> 5;          // 0..7
        if (k < BWk) {
            #pragma unroll
            for (int i = 0; i < 24; ++i) {
                const int j = i >> 2;
                const int n = (8 * i + nb) & 31;
                int cx = cxbase + j;
                cx = (cx < 0) ? 0 : ((cx > Dd - 1) ? Dd - 1 : cx);
                const int rb = (n * 4096 + cx) * BWk;
                const float v0 = pw[rb + y0c * (Dd * BWk) + k];
                const float v1 = pw[rb + y1c * (Dd * BWk) + k];
                wY[j * WJS + k * WN + n] = fmaf(fy, v1 - v0, v0);
            }
        }
    }
    __syncthreads();

    // --- main loop: per k, x-interp weights in registers + 8x8 FMA ---
    float acc[8][8];
    #pragma unroll
    for (int a = 0; a < 8; ++a)
        #pragma unroll
        for (int b = 0; b < 8; ++b) acc[a][b] = 0.f;

    // coarse-x left neighbor (relative, block-independent) + x frac
    const int j0 = (xi >> 2) + (((xi & 3) < 2) ? 0 : 1);      // 0..4
    const float fx = 0.125f + 0.25f * (float)(((xi & 3) + 2) & 3);

    const float* xpp = xp + xi * XSTR + bg * 8;
    const float* wap = wY + j0 * WJS + ng * 8;

    #pragma unroll 2
    for (int k = 0; k < BWk; ++k) {
        const float4 xv0 = *(const float4*)(xpp);
        const float4 xv1 = *(const float4*)(xpp + 4);
        const float4 a0  = *(const float4*)(wap);
        const float4 a1  = *(const float4*)(wap + 4);
        const float4 b0  = *(const float4*)(wap + WJS);
        const float4 b1  = *(const float4*)(wap + WJS + 4);
        xpp += XSTR; wap += WN;

        float xr[8], wr[8];
        xr[0] = xv0.x; xr[1] = xv0.y; xr[2] = xv0.z; xr[3] = xv0.w;
        xr[4] = xv1.x; xr[5] = xv1.y; xr[6] = xv1.z; xr[7] = xv1.w;
        wr[0] = fmaf(fx, b0.x - a0.x, a0.x);
        wr[1] = fmaf(fx, b0.y - a0.y, a0.y);
        wr[2] = fmaf(fx, b0.z - a0.z, a0.z);
        wr[3] = fmaf(fx, b0.w - a0.w, a0.w);
        wr[4] = fmaf(fx, b1.x - a1.x, a1.x);
        wr[5] = fmaf(fx, b1.y - a1.y, a1.y);
        wr[6] = fmaf(fx, b1.z - a1.z, a1.z);
        wr[7] = fmaf(fx, b1.w - a1.w, a1.w);

        #pragma unroll
        for (int bi = 0; bi < 8; ++bi)
            #pragma unroll
            for (int nj = 0; nj < 8; ++nj)
                acc[bi][nj] = fmaf(xr[bi], wr[nj], acc[bi][nj]);
    }

    // --- epilogue: nontemporal streaming stores, x-contiguous lanes ---
    const int bc0 = bg * 8, n0 = ng * 8;
    const int xg  = x0 + xi;
    float* obase = out + (size_t)(bc0 * N_PSF + n0) * (Hh * Ww) + y * Ww + xg;
    #pragma unroll
    for (int bi = 0; bi < 8; ++bi)
        #pragma unroll
        for (int nj = 0; nj < 8; ++nj)
            __builtin_nontemporal_store(acc[bi][nj],
                obase + (size_t)(bi * N_PSF + nj) * (Hh * Ww));
}

extern "C" void kernel_launch(void* const* d_in, const int* in_sizes, int n_in,
                              void* d_out, int out_size, void* d_ws, size_t ws_size,
                              hipStream_t stream) {
    const float* pw = (const float*)d_in[0];   // pre_weights [32,4096,31]
    const float* x  = (const float*)d_in[1];   // x [4,8,256,256]
    float* out = (float*)d_out;                // [32,32,256,256] f32

    dim3 grid(Ww / PX, Hh, 1);
    dim3 block(NTH, 1, 1);
    band_kernel<<<grid, block, 0, stream>>>(pw, x, out);
}

// Round 3
// 100.633 us; speedup vs baseline: 1.9161x; 1.9161x over previous
//
#include <hip/hip_runtime.h>

#define N_PSF 32
#define BC    32
#define Hh    256
#define Ww    256
#define Dd    64              // coarse spatial dim (256/4)
#define BWk   31              // band width
#define PADk  15
#define PX    16              // pixels per block
#define XW    (PX + BWk - 1)  // 46 staged x positions
#define XSTR  36              // xp LDS stride: mult of 4 (b128 align), ≡4 mod 32 (bank spread)
#define WN    36              // wY n-stride (same constraints)
#define WJS   (BWk * WN)      // 1116: per-coarse-x stride
#define NTH   256

__global__ __launch_bounds__(NTH, 3)
void band_kernel(const float* __restrict__ pw,
                 const float* __restrict__ x,
                 float* __restrict__ out)
{
    // wY: [j=6 coarse-x][k=31][n=32(+pad)]  y-interpolated weights
    // xp: [xw=46][bc=32(+pad)]              zero-padded x window
    __shared__ __align__(16) float smem[6 * WJS + XW * XSTR];
    float* wY = smem;
    float* xp = smem + 6 * WJS;

    const int tid = threadIdx.x;
    const int y   = blockIdx.y;
    const int x0  = blockIdx.x * PX;

    const int xi = tid & 15;              // pixel within tile
    const int ng = (tid >> 4) & 3;        // n-group (8 n)
    const int bg = tid >> 6;              // bc-group (8 bc) == wave id

    // --- y interpolation setup (block-uniform), exact scale-4 half-pixel ---
    const int yq = y >> 2, ry = y & 3;
    const int y0i = yq + ((ry < 2) ? -1 : 0);
    const float fy = 0.125f + 0.25f * (float)((ry + 2) & 3);  // {.625,.875,.125,.375}
    const int y0c = (y0i < 0) ? 0 : y0i;
    const int y1c = (y0i + 1 > Dd - 1) ? Dd - 1 : (y0i + 1);
    const int cxbase = (x0 >> 2) - 1;     // leftmost coarse col needed

    // --- stage x window: xp[xw][bc], zero-padded ---
    #pragma unroll
    for (int i = 0; i < 6; ++i) {
        int t = tid + i * NTH;
        if (t < XW * BC) {
            int xw = t % XW;
            int bc = t / XW;
            int gx = x0 - PADk + xw;
            float v = 0.f;
            if ((unsigned)gx < (unsigned)Ww) v = x[(bc * Hh + y) * Ww + gx];
            xp[xw * XSTR + bc] = v;
        }
    }

    // --- stage y-interpolated coarse weights: wY[j][k][n] ---
    // tasks: (j 0..5) x (n 0..31) x (k 0..30); lanes walk k => coalesced rows
    {
        const int k  = tid & 31;
        const int nb = tid >> 5;          // 0..7
        if (k < BWk) {
            #pragma unroll 8
            for (int i = 0; i < 24; ++i) {
                const int j = i >> 2;
                const int n = (8 * i + nb) & 31;
                int cx = cxbase + j;
                cx = (cx < 0) ? 0 : ((cx > Dd - 1) ? Dd - 1 : cx);
                const int rb = (n * 4096 + cx) * BWk;
                const float v0 = pw[rb + y0c * (Dd * BWk) + k];
                const float v1 = pw[rb + y1c * (Dd * BWk) + k];
                wY[j * WJS + k * WN + n] = fmaf(fy, v1 - v0, v0);
            }
        }
    }
    __syncthreads();

    // --- main loop: per k, x-interp weights in registers + 8x8 FMA ---
    float acc[8][8];
    #pragma unroll
    for (int a = 0; a < 8; ++a)
        #pragma unroll
        for (int b = 0; b < 8; ++b) acc[a][b] = 0.f;

    // coarse-x left neighbor (relative, block-independent) + x frac
    const int j0 = (xi >> 2) + (((xi & 3) < 2) ? 0 : 1);      // 0..4
    const float fx = 0.125f + 0.25f * (float)(((xi & 3) + 2) & 3);

    const float* xpp = xp + xi * XSTR + bg * 8;
    const float* wap = wY + j0 * WJS + ng * 8;

    #pragma unroll 2
    for (int k = 0; k < BWk; ++k) {
        const float4 xv0 = *(const float4*)(xpp);
        const float4 xv1 = *(const float4*)(xpp + 4);
        const float4 a0  = *(const float4*)(wap);
        const float4 a1  = *(const float4*)(wap + 4);
        const float4 b0  = *(const float4*)(wap + WJS);
        const float4 b1  = *(const float4*)(wap + WJS + 4);
        xpp += XSTR; wap += WN;

        float xr[8], wr[8];
        xr[0] = xv0.x; xr[1] = xv0.y; xr[2] = xv0.z; xr[3] = xv0.w;
        xr[4] = xv1.x; xr[5] = xv1.y; xr[6] = xv1.z; xr[7] = xv1.w;
        wr[0] = fmaf(fx, b0.x - a0.x, a0.x);
        wr[1] = fmaf(fx, b0.y - a0.y, a0.y);
        wr[2] = fmaf(fx, b0.z - a0.z, a0.z);
        wr[3] = fmaf(fx, b0.w - a0.w, a0.w);
        wr[4] = fmaf(fx, b1.x - a1.x, a1.x);
        wr[5] = fmaf(fx, b1.y - a1.y, a1.y);
        wr[6] = fmaf(fx, b1.z - a1.z, a1.z);
        wr[7] = fmaf(fx, b1.w - a1.w, a1.w);

        #pragma unroll
        for (int bi = 0; bi < 8; ++bi)
            #pragma unroll
            for (int nj = 0; nj < 8; ++nj)
                acc[bi][nj] = fmaf(xr[bi], wr[nj], acc[bi][nj]);
    }

    // --- epilogue: nontemporal streaming stores, x-contiguous lanes ---
    const int bc0 = bg * 8, n0 = ng * 8;
    const int xg  = x0 + xi;
    float* obase = out + (size_t)(bc0 * N_PSF + n0) * (Hh * Ww) + y * Ww + xg;
    #pragma unroll
    for (int bi = 0; bi < 8; ++bi)
        #pragma unroll
        for (int nj = 0; nj < 8; ++nj)
            __builtin_nontemporal_store(acc[bi][nj],
                obase + (size_t)(bi * N_PSF + nj) * (Hh * Ww));
}

extern "C" void kernel_launch(void* const* d_in, const int* in_sizes, int n_in,
                              void* d_out, int out_size, void* d_ws, size_t ws_size,
                              hipStream_t stream) {
    const float* pw = (const float*)d_in[0];   // pre_weights [32,4096,31]
    const float* x  = (const float*)d_in[1];   // x [4,8,256,256]
    float* out = (float*)d_out;                // [32,32,256,256] f32

    dim3 grid(Ww / PX, Hh, 1);
    dim3 block(NTH, 1, 1);
    band_kernel<<<grid, block, 0, stream>>>(pw, x, out);
}

// Round 4
// 93.788 us; speedup vs baseline: 2.0560x; 1.0730x over previous
//
#include <hip/hip_runtime.h>
#include <hip/hip_bf16.h>

#define Dd   64
#define BWk  31
#define PX   16
#define NTH  256
#define NS   40                 // wYb k-stride in bf16 units (multiple of 8 -> 16B aligned frags)
#define JS   (32 * NS)          // per-j stride

typedef float  f32x4   __attribute__((ext_vector_type(4)));
typedef short  bf16x8  __attribute__((ext_vector_type(8)));
typedef float  float4a __attribute__((ext_vector_type(4), aligned(4)));

__device__ __forceinline__ unsigned pk2(float lo, float hi) {
    __hip_bfloat162 h = __float22bfloat162_rn(make_float2(lo, hi));
    union { __hip_bfloat162 h; unsigned u; } c; c.h = h; return c.u;
}

__global__ __launch_bounds__(NTH, 3)
void band_mfma(const float* __restrict__ pw,
               const float* __restrict__ x,
               float* __restrict__ out)
{
    // y-interpolated coarse weights, bf16: [j=6][n=32][k=32 (pad k31=0), stride 40]
    __shared__ unsigned short wYb[6 * JS];

    const int tid = threadIdx.x;
    const int bx  = blockIdx.x;
    const int y   = blockIdx.y;
    const int x0  = bx * PX;

    // exact scale-4 half-pixel y interpolation (validated rounds 1-3)
    const int yq = y >> 2, ry = y & 3;
    const int y0i = yq + ((ry < 2) ? -1 : 0);
    const float fy = 0.125f + 0.25f * (float)((ry + 2) & 3);
    const int y0c = (y0i < 0) ? 0 : y0i;
    const int y1c = (y0i + 1 > Dd - 1) ? Dd - 1 : (y0i + 1);
    const int cxbase = (x0 >> 2) - 1;

    // ---- stage wYb: task = (n = tid>>3, k0 = (tid&7)*4) x (j 0..5) ----
    {
        const int k0 = (tid & 7) << 2;          // 0,4,...,28
        const int n  = tid >> 3;                // 0..31
        const bool lastk = (k0 == 28);
        #pragma unroll
        for (int j = 0; j < 6; ++j) {
            int cx = cxbase + j;
            cx = (cx < 0) ? 0 : ((cx > Dd - 1) ? Dd - 1 : cx);
            const size_t rb = ((size_t)n * 4096 + (size_t)cx) * BWk + k0;
            float4a a = *(const float4a*)(pw + rb + (size_t)y0c * (Dd * BWk));
            float4a b = *(const float4a*)(pw + rb + (size_t)y1c * (Dd * BWk));
            float v0 = fmaf(fy, b.x - a.x, a.x);
            float v1 = fmaf(fy, b.y - a.y, a.y);
            float v2 = fmaf(fy, b.z - a.z, a.z);
            float v3 = lastk ? 0.f : fmaf(fy, b.w - a.w, a.w);   // k=31 pad = 0
            *(uint2*)&wYb[j * JS + n * NS + k0] = make_uint2(pk2(v0, v1), pk2(v2, v3));
        }
    }
    __syncthreads();

    const int lane = tid & 63;
    const int px   = lane & 15;      // MFMA column = pixel; also A row index (n_psf low 4 bits)
    const int q    = lane >> 4;      // k-slice / C row group

    // A-frags: A[j][mh] = wY_j[n = mh*16 + (lane&15)][k = 8q..8q+7]  (register-cached)
    bf16x8 A[6][2];
    #pragma unroll
    for (int j = 0; j < 6; ++j) {
        A[j][0] = *(const bf16x8*)&wYb[j * JS + px * NS + q * 8];
        A[j][1] = *(const bf16x8*)&wYb[j * JS + (16 + px) * NS + q * 8];
    }

    // per-pixel x-interp coefficients c_j (2 of 6 nonzero)
    const int rx = px & 3;           // (x0+px)&3 == px&3 since x0 % 16 == 0
    const float fx = 0.125f + 0.25f * (float)((rx + 2) & 3);
    const int j0 = (px >> 2) + ((rx < 2) ? 0 : 1);   // 0..4
    float c[6];
    #pragma unroll
    for (int j = 0; j < 6; ++j)
        c[j] = (j == j0) ? (1.f - fx) : ((j == j0 + 1) ? fx : 0.f);

    const int bc0 = (tid >> 6) * 8;                 // 8 bc per wave
    const int gxb = x0 + px + q * 8 - 15;           // B element i -> x[gxb + i]
    const bool edgeblk = (bx == 0) || (bx == 15);
    const size_t yoff = (size_t)y * 256 + (size_t)(x0 + px);
    const f32x4 zero = {0.f, 0.f, 0.f, 0.f};

    #pragma unroll 2
    for (int b = 0; b < 8; ++b) {
        const int bc = bc0 + b;
        const float* xrow = x + ((size_t)bc * 256 + y) * 256;

        // B-frag: Hankel column px, k-slice q  (direct from global, L1/L2-hot)
        float xv[8];
        if (!edgeblk) {
            float4a v0 = *(const float4a*)(xrow + gxb);
            float4a v1 = *(const float4a*)(xrow + gxb + 4);
            xv[0] = v0.x; xv[1] = v0.y; xv[2] = v0.z; xv[3] = v0.w;
            xv[4] = v1.x; xv[5] = v1.y; xv[6] = v1.z; xv[7] = v1.w;
        } else {
            #pragma unroll
            for (int i = 0; i < 8; ++i) {
                int gx = gxb + i;
                xv[i] = ((unsigned)gx < 256u) ? xrow[gx] : 0.f;
            }
        }
        union { unsigned u[4]; bf16x8 v; } bb;
        bb.u[0] = pk2(xv[0], xv[1]);
        bb.u[1] = pk2(xv[2], xv[3]);
        bb.u[2] = pk2(xv[4], xv[5]);
        bb.u[3] = pk2(xv[6], xv[7]);
        const bf16x8 B = bb.v;

        #pragma unroll
        for (int mh = 0; mh < 2; ++mh) {
            f32x4 acc = zero;
            #pragma unroll
            for (int j = 0; j < 6; ++j) {
                f32x4 g = __builtin_amdgcn_mfma_f32_16x16x32_bf16(
                              A[j][mh], B, zero, 0, 0, 0);
                acc += g * c[j];               // x-interp blend, exact in f32
            }
            // C layout: col = lane&15 = px, row = 4q + reg  -> n_psf = mh*16 + 4q + reg
            float* p = out + (size_t)(bc * 32 + mh * 16 + q * 4) * 65536 + yoff;
            __builtin_nontemporal_store(acc.x, p);
            __builtin_nontemporal_store(acc.y, p + 65536);
            __builtin_nontemporal_store(acc.z, p + 131072);
            __builtin_nontemporal_store(acc.w, p + 196608);
        }
    }
}

extern "C" void kernel_launch(void* const* d_in, const int* in_sizes, int n_in,
                              void* d_out, int out_size, void* d_ws, size_t ws_size,
                              hipStream_t stream) {
    const float* pw = (const float*)d_in[0];   // pre_weights [32,4096,31]
    const float* x  = (const float*)d_in[1];   // x [4,8,256,256] -> [32,256,256]
    float* out = (float*)d_out;                // [32,32,256,256] f32

    dim3 grid(256 / PX, 256, 1);
    dim3 block(NTH, 1, 1);
    band_mfma<<<grid, block, 0, stream>>>(pw, x, out);
}